// Round 3
// baseline (26.009 us; speedup 1.0000x reference)
//
#include <hip/hip_runtime.h>

// StaticSceneFeatureExtractorGrid — v3: binned candidates.
// Kernel A (1 block): counting-sort scene points into 32x32 coarse bins -> ws.
// Kernel B (512 blocks x 512 thr): per-ped candidate scan over <=5x5 bins,
//   then attention + softmax + gated awe + LSTM cell (as v2, att2 64-lane).

constexpr int CELLS = 64;   // 8x8 ped grid
constexpr int HD    = 64;   // H_DIM
constexpr int AD    = 32;   // ATT_DIM
constexpr int PPB   = 4;    // peds per block
constexpr int BLK   = 512;  // threads per block (8 waves)

constexpr int   GB   = 32;          // coarse bins per axis
constexpr int   NB   = GB * GB;     // 1024 bins
constexpr float EXT  = 8.0f;        // extent [-8,8)
constexpr float BINV = 2.0f;        // 1 / 0.5 bin size

__device__ __forceinline__ int bin1d(float x) {
    int b = (int)floorf((x + EXT) * BINV);
    return min(max(b, 0), GB - 1);
}

// ---------------------------------------------------------------------------
__global__ __launch_bounds__(1024) void bin_points_kernel(
    const float* __restrict__ scene, int npts,
    float2* __restrict__ pts_out, unsigned* __restrict__ bin_start)
{
    __shared__ unsigned cnt[NB];
    __shared__ unsigned bufA[NB], bufB[NB];
    const int tid = threadIdx.x;

    cnt[tid] = 0u;
    __syncthreads();

    const float2* sc2 = reinterpret_cast<const float2*>(scene);
    for (int i = tid; i < npts; i += 1024) {
        float2 s = sc2[i];
        atomicAdd(&cnt[bin1d(s.y) * GB + bin1d(s.x)], 1u);
    }
    __syncthreads();

    // inclusive scan over 1024 bins (Hillis-Steele, ping-pong)
    unsigned own = cnt[tid];
    bufA[tid] = own;
    __syncthreads();
    unsigned* src = bufA; unsigned* dst = bufB;
    for (int off = 1; off < NB; off <<= 1) {
        unsigned v = src[tid];
        if (tid >= off) v += src[tid - off];
        dst[tid] = v;
        __syncthreads();
        unsigned* t = src; src = dst; dst = t;
    }
    unsigned incl = src[tid];
    bin_start[tid + 1] = incl;
    if (tid == 0) bin_start[0] = 0u;

    cnt[tid] = incl - own;          // scatter cursor = exclusive prefix
    __syncthreads();

    for (int i = tid; i < npts; i += 1024) {
        float2 s = sc2[i];
        unsigned slot = atomicAdd(&cnt[bin1d(s.y) * GB + bin1d(s.x)], 1u);
        pts_out[slot] = s;
    }
}

// ---------------------------------------------------------------------------
__global__ __launch_bounds__(BLK) void fused_ssfe_kernel(
    const float2* __restrict__ pts,        // sorted scene points (ws)
    const unsigned* __restrict__ bin_start,// [NB+1] (ws)
    const float* __restrict__ end_pos,     // [nped,2]
    const float* __restrict__ disp_pos,    // [nped,2]
    const float* __restrict__ h_in,        // [nped,64]
    const float* __restrict__ W_enc,       // [1,32]
    const float* __restrict__ b_enc,       // [32]
    const float* __restrict__ W_dec,       // [64,32]
    const float* __restrict__ b_dec,       // [32]
    const float* __restrict__ W_full,      // [32,1]
    const float* __restrict__ b_full,      // [1]
    const float* __restrict__ W_fbeta,     // [64,1]
    const float* __restrict__ b_fbeta,     // [1]
    const float* __restrict__ W_emb,       // [4,4]
    const float* __restrict__ b_emb,       // [4]
    const float* __restrict__ W_ih,        // [5,256]
    const float* __restrict__ b_ih,        // [256]
    const float* __restrict__ W_hh,        // [64,256]
    const float* __restrict__ b_hh,        // [256]
    float* __restrict__ out,               // [nped,64]
    int nped)
{
    __shared__ unsigned hist[PPB][CELLS];
    __shared__ float    h_s[PPB][HD];
    __shared__ float    att2_s[PPB][AD];   // b_dec + b_enc folded in
    __shared__ float    gate_s[PPB];
    __shared__ float    x_s[PPB][8];       // [0..3]=emb, [4]=gated awe
    __shared__ float    part[PPB][3][HD];  // half=1 LSTM partials

    const int tid  = threadIdx.x;
    const int ped0 = blockIdx.x * PPB;
    const int wave = tid >> 6;    // 0..7
    const int lane = tid & 63;
    const int p    = wave & 3;
    const int half = wave >> 2;   // 0 or 1
    const int ped  = ped0 + p;

    if (tid < PPB * CELLS) ((unsigned*)hist)[tid] = 0u;
    if (tid < PPB * HD) {
        int pp = tid >> 6, k = tid & 63;
        int pd = ped0 + pp;
        h_s[pp][k] = (pd < nped) ? h_in[pd * HD + k] : 0.f;
    }

    // this wave's pedestrian box (bit-exact vs JAX rounding)
    float px, py;
    if (ped < nped) { px = end_pos[ped * 2]; py = end_pos[ped * 2 + 1]; }
    else            { px = 1e30f;            py = 1e30f; }
    const float tlx = px - 1.0f, tly = py + 1.0f;
    const float brx = px + 1.0f, bry = py - 1.0f;
    __syncthreads();

    // ---- Phase 1: candidate scan over coarse bins --------------------------
    {
        const int bx0 = bin1d(tlx), bx1 = bin1d(brx);
        const int by0 = bin1d(bry), by1 = bin1d(tly);
        const unsigned lo = (unsigned)(half * 64 + lane);
        for (int by = by0; by <= by1; ++by) {
            const int rb = by * GB;
            const unsigned s = bin_start[rb + bx0];
            const unsigned e = bin_start[rb + bx1 + 1];
            for (unsigned i = s + lo; i < e; i += 128u) {
                float2 pt = pts[i];
                bool outside = (pt.x >= brx) | (pt.x <= tlx) |
                               (pt.y >= tly) | (pt.y <= bry);
                if (!outside) {
                    float cx = floorf((pt.x - tlx) * 4.0f);
                    float cy = floorf((tly - pt.y) * 4.0f);
                    int cell = (int)(cx + cy * 8.0f);
                    atomicAdd(&hist[p][cell], 1u);
                }
            }
        }
    }
    __syncthreads();

    // ---- Phase 2 ------------------------------------------------------------
    if (half == 0) {
        // waves 0-3: att2[j] = h . W_dec[:,j]; all 64 lanes (k split in halves)
        if (ped < nped) {
            const int col   = lane & 31;
            const int kbase = (lane >> 5) * 32;
            float a = 0.f;
            #pragma unroll 8
            for (int k = 0; k < 32; ++k) {
                int kk = kbase + k;
                a = fmaf(h_s[p][kk], W_dec[kk * AD + col], a);
            }
            a += __shfl_xor(a, 32, 64);
            if (lane < AD) att2_s[p][lane] = a + b_dec[lane] + b_enc[lane];
        }
    } else {
        // waves 4-7: gate = sigmoid(h . W_fbeta + b_fbeta)
        if (ped < nped) {
            float gp = h_s[p][lane] * W_fbeta[lane];
            #pragma unroll
            for (int off = 32; off; off >>= 1) gp += __shfl_xor(gp, off, 64);
            if (lane == 0) gate_s[p] = 1.f / (1.f + __expf(-(gp + b_fbeta[0])));
        }
    }
    __syncthreads();

    if (half == 0 && ped < nped) {
        // att[c] = sum_j relu(cnt*W_enc[j] + (b_enc[j]+att2[j])) * W_full[j] + b_full
        float cnt = (float)hist[p][lane];
        float att = b_full[0];
        #pragma unroll 8
        for (int j = 0; j < AD; ++j) {
            float s = fmaf(cnt, W_enc[j], att2_s[p][j]);
            att = fmaf(fmaxf(s, 0.f), W_full[j], att);
        }
        // softmax over 64 cells (one wave)
        float m = att;
        #pragma unroll
        for (int off = 32; off; off >>= 1) m = fmaxf(m, __shfl_xor(m, off, 64));
        float e = __expf(att - m);
        float ssum = e;
        #pragma unroll
        for (int off = 32; off; off >>= 1) ssum += __shfl_xor(ssum, off, 64);
        float awe = cnt * e / ssum;
        #pragma unroll
        for (int off = 32; off; off >>= 1) awe += __shfl_xor(awe, off, 64);

        if (lane < 4) {
            float ex = end_pos[ped * 2], ey = end_pos[ped * 2 + 1];
            float dx = disp_pos[ped * 2], dy = disp_pos[ped * 2 + 1];
            x_s[p][lane] = ex * W_emb[0 * 4 + lane] + ey * W_emb[1 * 4 + lane]
                         + dx * W_emb[2 * 4 + lane] + dy * W_emb[3 * 4 + lane]
                         + b_emb[lane];
        }
        if (lane == 4) x_s[p][4] = gate_s[p] * awe;
    }
    __syncthreads();

    // ---- LSTM gates: K split across wave pairs (p, p+4) --------------------
    if (ped < nped) {
        float acc_i, acc_g, acc_o;
        if (half == 0) {
            acc_i = b_ih[lane]       + b_hh[lane];
            acc_g = b_ih[128 + lane] + b_hh[128 + lane];
            acc_o = b_ih[192 + lane] + b_hh[192 + lane];
            #pragma unroll
            for (int k = 0; k < 5; ++k) {
                float xk = x_s[p][k];
                acc_i = fmaf(xk, W_ih[k * 256 + lane],       acc_i);
                acc_g = fmaf(xk, W_ih[k * 256 + 128 + lane], acc_g);
                acc_o = fmaf(xk, W_ih[k * 256 + 192 + lane], acc_o);
            }
        } else {
            acc_i = 0.f; acc_g = 0.f; acc_o = 0.f;
        }
        const int k0 = half * 32;
        #pragma unroll 8
        for (int k = k0; k < k0 + 32; ++k) {
            float hk = h_s[p][k];
            acc_i = fmaf(hk, W_hh[k * 256 + lane],       acc_i);
            acc_g = fmaf(hk, W_hh[k * 256 + 128 + lane], acc_g);
            acc_o = fmaf(hk, W_hh[k * 256 + 192 + lane], acc_o);
        }
        if (half == 1) {
            part[p][0][lane] = acc_i;
            part[p][1][lane] = acc_g;
            part[p][2][lane] = acc_o;
        }
        __syncthreads();
        if (half == 0) {
            acc_i += part[p][0][lane];
            acc_g += part[p][1][lane];
            acc_o += part[p][2][lane];
            float sig_i = 1.f / (1.f + __expf(-acc_i));
            float sig_o = 1.f / (1.f + __expf(-acc_o));
            float cc = sig_i * tanhf(acc_g);
            out[ped * HD + lane] = sig_o * tanhf(cc);
        }
    } else {
        __syncthreads();   // keep barrier uniform across the block
    }
}

// ---------------------------------------------------------------------------
extern "C" void kernel_launch(void* const* d_in, const int* in_sizes, int n_in,
                              void* d_out, int out_size, void* d_ws, size_t ws_size,
                              hipStream_t stream)
{
    const float* scene   = (const float*)d_in[0];
    const float* end_pos = (const float*)d_in[1];
    const float* disp    = (const float*)d_in[2];
    const float* h_in    = (const float*)d_in[3];
    const float* W_enc   = (const float*)d_in[4];
    const float* b_enc   = (const float*)d_in[5];
    const float* W_dec   = (const float*)d_in[6];
    const float* b_dec   = (const float*)d_in[7];
    const float* W_full  = (const float*)d_in[8];
    const float* b_full  = (const float*)d_in[9];
    const float* W_fbeta = (const float*)d_in[10];
    const float* b_fbeta = (const float*)d_in[11];
    const float* W_emb   = (const float*)d_in[12];
    const float* b_emb   = (const float*)d_in[13];
    const float* W_ih    = (const float*)d_in[14];
    const float* b_ih    = (const float*)d_in[15];
    const float* W_hh    = (const float*)d_in[16];
    const float* b_hh    = (const float*)d_in[17];
    float* out = (float*)d_out;

    const int nped = in_sizes[1] / 2;
    const int npts = in_sizes[0] / 2;

    // ws layout: [0) sorted float2 points (npts), then bin_start (NB+1 uints)
    float2*   pts_ws  = (float2*)d_ws;
    unsigned* bins_ws = (unsigned*)((char*)d_ws + (size_t)npts * sizeof(float2));

    hipLaunchKernelGGL(bin_points_kernel, dim3(1), dim3(1024), 0, stream,
        scene, npts, pts_ws, bins_ws);

    const int blocks = (nped + PPB - 1) / PPB;
    hipLaunchKernelGGL(fused_ssfe_kernel, dim3(blocks), dim3(BLK), 0, stream,
        pts_ws, bins_ws, end_pos, disp, h_in, W_enc, b_enc, W_dec, b_dec,
        W_full, b_full, W_fbeta, b_fbeta, W_emb, b_emb, W_ih, b_ih, W_hh, b_hh,
        out, nped);
}

// Round 4
// 17.444 us; speedup vs baseline: 1.4910x; 1.4910x over previous
//
#include <hip/hip_runtime.h>

// StaticSceneFeatureExtractorGrid — v4: single kernel, wave-specialized.
// 1024 blocks x 256 threads (4 waves), 2 peds/block.
// Phase 1: LDS histogram, float4 scene loads.
// Phase 2: waves 0-1 (per-ped): att2 -> att -> softmax -> awe -> gate -> x,
//          concurrently waves 2-3: LSTM k in [32,64) partials.
// 3 barriers total; x kept in registers; fast exp/rcp transcendentals.

constexpr int CELLS = 64;   // 8x8 ped grid
constexpr int HD    = 64;   // H_DIM
constexpr int AD    = 32;   // ATT_DIM
constexpr int PPB   = 2;    // peds per block
constexpr int BLK   = 256;  // threads per block (4 waves)

__device__ __forceinline__ float fsig(float x) {
    return __builtin_amdgcn_rcpf(1.f + __expf(-x));
}
__device__ __forceinline__ float ftanh(float x) {
    float e = __expf(2.f * x);
    return 1.f - 2.f * __builtin_amdgcn_rcpf(e + 1.f);
}

__global__ __launch_bounds__(BLK, 4) void fused_ssfe_kernel(
    const float* __restrict__ scene,     // [npts,2]
    const float* __restrict__ end_pos,   // [nped,2]
    const float* __restrict__ disp_pos,  // [nped,2]
    const float* __restrict__ h_in,      // [nped,64]
    const float* __restrict__ W_enc,     // [1,32]
    const float* __restrict__ b_enc,     // [32]
    const float* __restrict__ W_dec,     // [64,32]
    const float* __restrict__ b_dec,     // [32]
    const float* __restrict__ W_full,    // [32,1]
    const float* __restrict__ b_full,    // [1]
    const float* __restrict__ W_fbeta,   // [64,1]
    const float* __restrict__ b_fbeta,   // [1]
    const float* __restrict__ W_emb,     // [4,4]
    const float* __restrict__ b_emb,     // [4]
    const float* __restrict__ W_ih,      // [5,256]
    const float* __restrict__ b_ih,      // [256]
    const float* __restrict__ W_hh,      // [64,256]
    const float* __restrict__ b_hh,      // [256]
    float* __restrict__ out,             // [nped,64]
    int nped, int npts)
{
    __shared__ unsigned hist[PPB][CELLS];
    __shared__ float    h_s[PPB][HD];
    __shared__ float    att2_s[PPB][AD];   // b_dec + b_enc folded in
    __shared__ float    part[PPB][3][HD];  // waves 2-3 LSTM partials

    const int tid  = threadIdx.x;
    const int ped0 = blockIdx.x * PPB;
    const int wave = tid >> 6;    // 0..3
    const int lane = tid & 63;
    const int p    = wave & 1;
    const int half = wave >> 1;   // 0: att path + LSTM low half; 1: LSTM high half
    const int ped  = ped0 + p;

    // zero histogram (PPB*CELLS == 128)
    if (tid < PPB * CELLS) ((unsigned*)hist)[tid] = 0u;
    // stage h (PPB*HD == 128)
    if (tid < PPB * HD) {
        int pp = tid >> 6, k = tid & 63;
        int pd = ped0 + pp;
        h_s[pp][k] = (pd < nped) ? h_in[pd * HD + k] : 0.f;
    }

    // ped boxes (block-uniform -> scalar regs). Bit-exact vs JAX rounding.
    float px0, py0, px1, py1;
    px0 = end_pos[ped0 * 2 + 0]; py0 = end_pos[ped0 * 2 + 1];
    if (ped0 + 1 < nped) { px1 = end_pos[ped0 * 2 + 2]; py1 = end_pos[ped0 * 2 + 3]; }
    else                 { px1 = 1e30f;                 py1 = 1e30f; }
    const float tlx0 = px0 - 1.0f, tly0 = py0 + 1.0f, brx0 = px0 + 1.0f, bry0 = py0 - 1.0f;
    const float tlx1 = px1 - 1.0f, tly1 = py1 + 1.0f, brx1 = px1 + 1.0f, bry1 = py1 - 1.0f;
    __syncthreads();

    // ---- Phase 1: histogram -------------------------------------------------
    {
        const float4* sc4 = reinterpret_cast<const float4*>(scene);
        const int n4 = npts >> 1;
        #pragma unroll 4
        for (int i = tid; i < n4; i += BLK) {
            float4 s = sc4[i];
            // point (x,y) vs ped0
            {
                bool o = (s.x >= brx0) | (s.x <= tlx0) | (s.y >= tly0) | (s.y <= bry0);
                if (!o) {
                    int c = (int)(floorf((s.x - tlx0) * 4.f) + floorf((tly0 - s.y) * 4.f) * 8.f);
                    atomicAdd(&hist[0][c], 1u);
                }
            }
            {
                bool o = (s.x >= brx1) | (s.x <= tlx1) | (s.y >= tly1) | (s.y <= bry1);
                if (!o) {
                    int c = (int)(floorf((s.x - tlx1) * 4.f) + floorf((tly1 - s.y) * 4.f) * 8.f);
                    atomicAdd(&hist[1][c], 1u);
                }
            }
            // point (z,w) vs ped0/ped1
            {
                bool o = (s.z >= brx0) | (s.z <= tlx0) | (s.w >= tly0) | (s.w <= bry0);
                if (!o) {
                    int c = (int)(floorf((s.z - tlx0) * 4.f) + floorf((tly0 - s.w) * 4.f) * 8.f);
                    atomicAdd(&hist[0][c], 1u);
                }
            }
            {
                bool o = (s.z >= brx1) | (s.z <= tlx1) | (s.w >= tly1) | (s.w <= bry1);
                if (!o) {
                    int c = (int)(floorf((s.z - tlx1) * 4.f) + floorf((tly1 - s.w) * 4.f) * 8.f);
                    atomicAdd(&hist[1][c], 1u);
                }
            }
        }
    }
    __syncthreads();

    float acc_i, acc_g, acc_o;

    if (half == 1) {
        // ---- waves 2-3: LSTM high half, k in [32,64) ------------------------
        if (ped < nped) {
            acc_i = 0.f; acc_g = 0.f; acc_o = 0.f;
            #pragma unroll 8
            for (int k = 32; k < 64; ++k) {
                float hk = h_s[p][k];
                acc_i = fmaf(hk, W_hh[k * 256 + lane],       acc_i);
                acc_g = fmaf(hk, W_hh[k * 256 + 128 + lane], acc_g);
                acc_o = fmaf(hk, W_hh[k * 256 + 192 + lane], acc_o);
            }
            part[p][0][lane] = acc_i;
            part[p][1][lane] = acc_g;
            part[p][2][lane] = acc_o;
        }
    } else if (ped < nped) {
        // ---- waves 0-1: attention path --------------------------------------
        // att2[j] = h . W_dec[:,j], 64 lanes (k split in halves)
        {
            const int col   = lane & 31;
            const int kbase = (lane >> 5) * 32;
            float a = 0.f;
            #pragma unroll 8
            for (int k = 0; k < 32; ++k) {
                int kk = kbase + k;
                a = fmaf(h_s[p][kk], W_dec[kk * AD + col], a);
            }
            a += __shfl_xor(a, 32, 64);
            if (lane < AD) att2_s[p][lane] = a + b_dec[lane] + b_enc[lane];
        }
        // att[c] = sum_j relu(cnt*W_enc[j] + att2[j]) * W_full[j] + b_full
        float cnt = (float)hist[p][lane];
        float att = b_full[0];
        #pragma unroll 8
        for (int j = 0; j < AD; ++j) {
            float s = fmaf(cnt, W_enc[j], att2_s[p][j]);
            att = fmaf(fmaxf(s, 0.f), W_full[j], att);
        }
        // softmax over 64 cells
        float m = att;
        #pragma unroll
        for (int off = 32; off; off >>= 1) m = fmaxf(m, __shfl_xor(m, off, 64));
        float e = __expf(att - m);
        float ssum = e;
        #pragma unroll
        for (int off = 32; off; off >>= 1) ssum += __shfl_xor(ssum, off, 64);
        float awe = cnt * e * __builtin_amdgcn_rcpf(ssum);
        #pragma unroll
        for (int off = 32; off; off >>= 1) awe += __shfl_xor(awe, off, 64);

        // gate (in-wave, all 64 lanes)
        float gp = h_s[p][lane] * W_fbeta[lane];
        #pragma unroll
        for (int off = 32; off; off >>= 1) gp += __shfl_xor(gp, off, 64);
        float gate = fsig(gp + b_fbeta[0]);
        float aweg = gate * awe;

        // x = [emb(4), gated awe]  (uniform values, registers)
        float dx = disp_pos[ped * 2], dy = disp_pos[ped * 2 + 1];
        float ex = (p == 0) ? px0 : px1;
        float ey = (p == 0) ? py0 : py1;
        float x0 = ex * W_emb[0]  + ey * W_emb[4]  + dx * W_emb[8]  + dy * W_emb[12] + b_emb[0];
        float x1 = ex * W_emb[1]  + ey * W_emb[5]  + dx * W_emb[9]  + dy * W_emb[13] + b_emb[1];
        float x2 = ex * W_emb[2]  + ey * W_emb[6]  + dx * W_emb[10] + dy * W_emb[14] + b_emb[2];
        float x3 = ex * W_emb[3]  + ey * W_emb[7]  + dx * W_emb[11] + dy * W_emb[15] + b_emb[3];

        // LSTM low half: biases + W_ih + W_hh k in [0,32)
        acc_i = b_ih[lane]       + b_hh[lane];
        acc_g = b_ih[128 + lane] + b_hh[128 + lane];
        acc_o = b_ih[192 + lane] + b_hh[192 + lane];
        acc_i = fmaf(x0, W_ih[0 * 256 + lane], acc_i);
        acc_g = fmaf(x0, W_ih[0 * 256 + 128 + lane], acc_g);
        acc_o = fmaf(x0, W_ih[0 * 256 + 192 + lane], acc_o);
        acc_i = fmaf(x1, W_ih[1 * 256 + lane], acc_i);
        acc_g = fmaf(x1, W_ih[1 * 256 + 128 + lane], acc_g);
        acc_o = fmaf(x1, W_ih[1 * 256 + 192 + lane], acc_o);
        acc_i = fmaf(x2, W_ih[2 * 256 + lane], acc_i);
        acc_g = fmaf(x2, W_ih[2 * 256 + 128 + lane], acc_g);
        acc_o = fmaf(x2, W_ih[2 * 256 + 192 + lane], acc_o);
        acc_i = fmaf(x3, W_ih[3 * 256 + lane], acc_i);
        acc_g = fmaf(x3, W_ih[3 * 256 + 128 + lane], acc_g);
        acc_o = fmaf(x3, W_ih[3 * 256 + 192 + lane], acc_o);
        acc_i = fmaf(aweg, W_ih[4 * 256 + lane], acc_i);
        acc_g = fmaf(aweg, W_ih[4 * 256 + 128 + lane], acc_g);
        acc_o = fmaf(aweg, W_ih[4 * 256 + 192 + lane], acc_o);
        #pragma unroll 8
        for (int k = 0; k < 32; ++k) {
            float hk = h_s[p][k];
            acc_i = fmaf(hk, W_hh[k * 256 + lane],       acc_i);
            acc_g = fmaf(hk, W_hh[k * 256 + 128 + lane], acc_g);
            acc_o = fmaf(hk, W_hh[k * 256 + 192 + lane], acc_o);
        }
    }
    __syncthreads();

    if (half == 0 && ped < nped) {
        acc_i += part[p][0][lane];
        acc_g += part[p][1][lane];
        acc_o += part[p][2][lane];
        float cc = fsig(acc_i) * ftanh(acc_g);
        out[ped * HD + lane] = fsig(acc_o) * ftanh(cc);
    }
}

extern "C" void kernel_launch(void* const* d_in, const int* in_sizes, int n_in,
                              void* d_out, int out_size, void* d_ws, size_t ws_size,
                              hipStream_t stream)
{
    const float* scene   = (const float*)d_in[0];
    const float* end_pos = (const float*)d_in[1];
    const float* disp    = (const float*)d_in[2];
    const float* h_in    = (const float*)d_in[3];
    const float* W_enc   = (const float*)d_in[4];
    const float* b_enc   = (const float*)d_in[5];
    const float* W_dec   = (const float*)d_in[6];
    const float* b_dec   = (const float*)d_in[7];
    const float* W_full  = (const float*)d_in[8];
    const float* b_full  = (const float*)d_in[9];
    const float* W_fbeta = (const float*)d_in[10];
    const float* b_fbeta = (const float*)d_in[11];
    const float* W_emb   = (const float*)d_in[12];
    const float* b_emb   = (const float*)d_in[13];
    const float* W_ih    = (const float*)d_in[14];
    const float* b_ih    = (const float*)d_in[15];
    const float* W_hh    = (const float*)d_in[16];
    const float* b_hh    = (const float*)d_in[17];
    float* out = (float*)d_out;

    const int nped = in_sizes[1] / 2;
    const int npts = in_sizes[0] / 2;
    const int blocks = (nped + PPB - 1) / PPB;

    hipLaunchKernelGGL(fused_ssfe_kernel, dim3(blocks), dim3(BLK), 0, stream,
        scene, end_pos, disp, h_in, W_enc, b_enc, W_dec, b_dec, W_full, b_full,
        W_fbeta, b_fbeta, W_emb, b_emb, W_ih, b_ih, W_hh, b_hh, out, nped, npts);
}

// Round 5
// 16.738 us; speedup vs baseline: 1.5538x; 1.0422x over previous
//
#include <hip/hip_runtime.h>

// StaticSceneFeatureExtractorGrid — v5: branchless histogram + 8 waves/SIMD.
// 1024 blocks x 512 threads (8 waves), 2 peds/block.
// Phase 1: float4 scene loads, branchless test -> ds_add (dummy-cell padded).
// Phase 2: per ped 4 waves: r0 attention path, r1-3 W_hh thirds, 1 barrier.

constexpr int HD    = 64;   // H_DIM
constexpr int AD    = 32;   // ATT_DIM
constexpr int PPB   = 2;    // peds per block
constexpr int BLK   = 512;  // threads per block (8 waves)
constexpr int HROW  = 128;  // 64 real cells + 64 dummy (bank-spread)

__device__ __forceinline__ float fsig(float x) {
    return __builtin_amdgcn_rcpf(1.f + __expf(-x));
}
__device__ __forceinline__ float ftanh(float x) {
    float e = __expf(2.f * x);
    return 1.f - 2.f * __builtin_amdgcn_rcpf(e + 1.f);
}

__global__ __launch_bounds__(BLK, 8) void fused_ssfe_kernel(
    const float* __restrict__ scene,     // [npts,2]
    const float* __restrict__ end_pos,   // [nped,2]
    const float* __restrict__ disp_pos,  // [nped,2]
    const float* __restrict__ h_in,      // [nped,64]
    const float* __restrict__ W_enc,     // [1,32]
    const float* __restrict__ b_enc,     // [32]
    const float* __restrict__ W_dec,     // [64,32]
    const float* __restrict__ b_dec,     // [32]
    const float* __restrict__ W_full,    // [32,1]
    const float* __restrict__ b_full,    // [1]
    const float* __restrict__ W_fbeta,   // [64,1]
    const float* __restrict__ b_fbeta,   // [1]
    const float* __restrict__ W_emb,     // [4,4]
    const float* __restrict__ b_emb,     // [4]
    const float* __restrict__ W_ih,      // [5,256]
    const float* __restrict__ b_ih,      // [256]
    const float* __restrict__ W_hh,      // [64,256]
    const float* __restrict__ b_hh,      // [256]
    float* __restrict__ out,             // [nped,64]
    int nped, int npts)
{
    __shared__ unsigned hist[PPB][HROW];
    __shared__ float    h_s[PPB][HD];
    __shared__ float    att2_s[PPB][AD];      // b_dec + b_enc folded in
    __shared__ float    part[PPB][3][3][HD];  // [ped][r-1][gate][lane]

    const int tid  = threadIdx.x;
    const int ped0 = blockIdx.x * PPB;
    const int wave = tid >> 6;    // 0..7
    const int lane = tid & 63;
    const int p    = wave & 1;    // ped within block
    const int r    = wave >> 1;   // role 0..3
    const int ped  = ped0 + p;

    // zero histograms (PPB*HROW == 256)
    if (tid < PPB * HROW) ((unsigned*)hist)[tid] = 0u;
    // stage h (PPB*HD == 128)
    if (tid < PPB * HD) {
        int pp = tid >> 6, k = tid & 63;
        int pd = ped0 + pp;
        h_s[pp][k] = (pd < nped) ? h_in[pd * HD + k] : 0.f;
    }

    // ped boxes (block-uniform). Bit-exact vs JAX rounding.
    float px0, py0, px1, py1;
    px0 = end_pos[ped0 * 2 + 0]; py0 = end_pos[ped0 * 2 + 1];
    if (ped0 + 1 < nped) { px1 = end_pos[ped0 * 2 + 2]; py1 = end_pos[ped0 * 2 + 3]; }
    else                 { px1 = 1e30f;                 py1 = 1e30f; }
    const float tlx0 = px0 - 1.0f, tly0 = py0 + 1.0f, brx0 = px0 + 1.0f, bry0 = py0 - 1.0f;
    const float tlx1 = px1 - 1.0f, tly1 = py1 + 1.0f, brx1 = px1 + 1.0f, bry1 = py1 - 1.0f;
    __syncthreads();

    // ---- Phase 1: branchless histogram -------------------------------------
    {
        const int dummy = 64 + lane;   // bank-spread discard slot
        auto test = [&](float sx, float sy, int pp,
                        float tlx, float tly, float brx, float bry) {
            // inside == exact complement of reference's outside (strict cmps)
            bool inside = (sx < brx) & (sx > tlx) & (sy < tly) & (sy > bry);
            float cx = floorf((sx - tlx) * 4.0f);
            float cy = floorf((tly - sy) * 4.0f);
            int c = (int)fmaf(cy, 8.0f, cx);       // exact: small ints in fp
            int idx = inside ? c : dummy;
            atomicAdd(&hist[pp][idx], 1u);
        };
        const float4* sc4 = reinterpret_cast<const float4*>(scene);
        const int n4 = npts >> 1;
        #pragma unroll 4
        for (int i = tid; i < n4; i += BLK) {
            float4 s = sc4[i];
            test(s.x, s.y, 0, tlx0, tly0, brx0, bry0);
            test(s.x, s.y, 1, tlx1, tly1, brx1, bry1);
            test(s.z, s.w, 0, tlx0, tly0, brx0, bry0);
            test(s.z, s.w, 1, tlx1, tly1, brx1, bry1);
        }
    }
    __syncthreads();

    float acc_i = 0.f, acc_g = 0.f, acc_o = 0.f;

    if (r != 0) {
        // ---- waves r=1..3: W_hh thirds ------------------------------------
        if (ped < nped) {
            int k0, k1;
            if      (r == 1) { k0 = 0;  k1 = 22; }
            else if (r == 2) { k0 = 22; k1 = 43; }
            else             { k0 = 43; k1 = 64; }
            for (int k = k0; k < k1; ++k) {
                float hk = h_s[p][k];
                acc_i = fmaf(hk, W_hh[k * 256 + lane],       acc_i);
                acc_g = fmaf(hk, W_hh[k * 256 + 128 + lane], acc_g);
                acc_o = fmaf(hk, W_hh[k * 256 + 192 + lane], acc_o);
            }
            part[p][r - 1][0][lane] = acc_i;
            part[p][r - 1][1][lane] = acc_g;
            part[p][r - 1][2][lane] = acc_o;
        }
    } else if (ped < nped) {
        // ---- wave r=0: attention path --------------------------------------
        // att2[j] = h . W_dec[:,j], 64 lanes (k split in halves)
        {
            const int col   = lane & 31;
            const int kbase = (lane >> 5) * 32;
            float a = 0.f;
            #pragma unroll 8
            for (int k = 0; k < 32; ++k) {
                int kk = kbase + k;
                a = fmaf(h_s[p][kk], W_dec[kk * AD + col], a);
            }
            a += __shfl_xor(a, 32, 64);
            if (lane < AD) att2_s[p][lane] = a + b_dec[lane] + b_enc[lane];
        }
        // att[c] = sum_j relu(cnt*W_enc[j] + att2[j]) * W_full[j] + b_full
        float cnt = (float)hist[p][lane];
        float att = b_full[0];
        #pragma unroll 8
        for (int j = 0; j < AD; ++j) {
            float s = fmaf(cnt, W_enc[j], att2_s[p][j]);
            att = fmaf(fmaxf(s, 0.f), W_full[j], att);
        }
        // softmax over 64 cells: max, then joint (e-sum, cnt*e-sum) reduction
        float m = att;
        #pragma unroll
        for (int off = 32; off; off >>= 1) m = fmaxf(m, __shfl_xor(m, off, 64));
        float e  = __expf(att - m);
        float se = e, sa = cnt * e;
        #pragma unroll
        for (int off = 32; off; off >>= 1) {
            se += __shfl_xor(se, off, 64);
            sa += __shfl_xor(sa, off, 64);
        }
        float awe = sa * __builtin_amdgcn_rcpf(se);

        // gate = sigmoid(h . W_fbeta + b_fbeta)
        float gp = h_s[p][lane] * W_fbeta[lane];
        #pragma unroll
        for (int off = 32; off; off >>= 1) gp += __shfl_xor(gp, off, 64);
        float aweg = fsig(gp + b_fbeta[0]) * awe;

        // x = [emb(4), gated awe] (uniform)
        float dx = disp_pos[ped * 2], dy = disp_pos[ped * 2 + 1];
        float ex = (p == 0) ? px0 : px1;
        float ey = (p == 0) ? py0 : py1;
        float x0 = ex * W_emb[0] + ey * W_emb[4] + dx * W_emb[8]  + dy * W_emb[12] + b_emb[0];
        float x1 = ex * W_emb[1] + ey * W_emb[5] + dx * W_emb[9]  + dy * W_emb[13] + b_emb[1];
        float x2 = ex * W_emb[2] + ey * W_emb[6] + dx * W_emb[10] + dy * W_emb[14] + b_emb[2];
        float x3 = ex * W_emb[3] + ey * W_emb[7] + dx * W_emb[11] + dy * W_emb[15] + b_emb[3];

        acc_i = b_ih[lane]       + b_hh[lane];
        acc_g = b_ih[128 + lane] + b_hh[128 + lane];
        acc_o = b_ih[192 + lane] + b_hh[192 + lane];
        acc_i = fmaf(x0, W_ih[0 * 256 + lane], acc_i);
        acc_g = fmaf(x0, W_ih[0 * 256 + 128 + lane], acc_g);
        acc_o = fmaf(x0, W_ih[0 * 256 + 192 + lane], acc_o);
        acc_i = fmaf(x1, W_ih[1 * 256 + lane], acc_i);
        acc_g = fmaf(x1, W_ih[1 * 256 + 128 + lane], acc_g);
        acc_o = fmaf(x1, W_ih[1 * 256 + 192 + lane], acc_o);
        acc_i = fmaf(x2, W_ih[2 * 256 + lane], acc_i);
        acc_g = fmaf(x2, W_ih[2 * 256 + 128 + lane], acc_g);
        acc_o = fmaf(x2, W_ih[2 * 256 + 192 + lane], acc_o);
        acc_i = fmaf(x3, W_ih[3 * 256 + lane], acc_i);
        acc_g = fmaf(x3, W_ih[3 * 256 + 128 + lane], acc_g);
        acc_o = fmaf(x3, W_ih[3 * 256 + 192 + lane], acc_o);
        acc_i = fmaf(aweg, W_ih[4 * 256 + lane], acc_i);
        acc_g = fmaf(aweg, W_ih[4 * 256 + 128 + lane], acc_g);
        acc_o = fmaf(aweg, W_ih[4 * 256 + 192 + lane], acc_o);
    }
    __syncthreads();

    if (r == 0 && ped < nped) {
        acc_i += part[p][0][0][lane] + part[p][1][0][lane] + part[p][2][0][lane];
        acc_g += part[p][0][1][lane] + part[p][1][1][lane] + part[p][2][1][lane];
        acc_o += part[p][0][2][lane] + part[p][1][2][lane] + part[p][2][2][lane];
        float cc = fsig(acc_i) * ftanh(acc_g);
        out[ped * HD + lane] = fsig(acc_o) * ftanh(cc);
    }
}

extern "C" void kernel_launch(void* const* d_in, const int* in_sizes, int n_in,
                              void* d_out, int out_size, void* d_ws, size_t ws_size,
                              hipStream_t stream)
{
    const float* scene   = (const float*)d_in[0];
    const float* end_pos = (const float*)d_in[1];
    const float* disp    = (const float*)d_in[2];
    const float* h_in    = (const float*)d_in[3];
    const float* W_enc   = (const float*)d_in[4];
    const float* b_enc   = (const float*)d_in[5];
    const float* W_dec   = (const float*)d_in[6];
    const float* b_dec   = (const float*)d_in[7];
    const float* W_full  = (const float*)d_in[8];
    const float* b_full  = (const float*)d_in[9];
    const float* W_fbeta = (const float*)d_in[10];
    const float* b_fbeta = (const float*)d_in[11];
    const float* W_emb   = (const float*)d_in[12];
    const float* b_emb   = (const float*)d_in[13];
    const float* W_ih    = (const float*)d_in[14];
    const float* b_ih    = (const float*)d_in[15];
    const float* W_hh    = (const float*)d_in[16];
    const float* b_hh    = (const float*)d_in[17];
    float* out = (float*)d_out;

    const int nped = in_sizes[1] / 2;
    const int npts = in_sizes[0] / 2;
    const int blocks = (nped + PPB - 1) / PPB;

    hipLaunchKernelGGL(fused_ssfe_kernel, dim3(blocks), dim3(BLK), 0, stream,
        scene, end_pos, disp, h_in, W_enc, b_enc, W_dec, b_dec, W_full, b_full,
        W_fbeta, b_fbeta, W_emb, b_emb, W_ih, b_ih, W_hh, b_hh, out, nped, npts);
}

// Round 6
// 16.421 us; speedup vs baseline: 1.5839x; 1.0193x over previous
//
#include <hip/hip_runtime.h>

// StaticSceneFeatureExtractorGrid — v6.
// 1024 blocks x 512 threads (8 waves), 2 peds/block, 8 waves/SIMD.
// Phase 1: branchless LDS histogram, float4 loads, SGPR-scalarized bounds.
// Phase 2: waves 0/1 = attention path (ped 0/1);
//          waves 2..7 = k-sixths of W_hh, each serving BOTH peds from one
//          W_hh load (halves W_hh L2 traffic); LDS partials, 1 barrier.

constexpr int HD    = 64;   // H_DIM
constexpr int AD    = 32;   // ATT_DIM
constexpr int PPB   = 2;    // peds per block
constexpr int BLK   = 512;  // threads per block (8 waves)
constexpr int HROW  = 128;  // 64 real cells + 64 dummy (bank-spread)

__device__ __forceinline__ float fsig(float x) {
    return __builtin_amdgcn_rcpf(1.f + __expf(-x));
}
__device__ __forceinline__ float ftanh(float x) {
    float e = __expf(2.f * x);
    return 1.f - 2.f * __builtin_amdgcn_rcpf(e + 1.f);
}
__device__ __forceinline__ float rfl(float x) {   // force wave-uniform -> SGPR
    return __int_as_float(__builtin_amdgcn_readfirstlane(__float_as_int(x)));
}

__global__ __launch_bounds__(BLK, 8) void fused_ssfe_kernel(
    const float* __restrict__ scene,     // [npts,2]
    const float* __restrict__ end_pos,   // [nped,2]
    const float* __restrict__ disp_pos,  // [nped,2]
    const float* __restrict__ h_in,      // [nped,64]
    const float* __restrict__ W_enc,     // [1,32]
    const float* __restrict__ b_enc,     // [32]
    const float* __restrict__ W_dec,     // [64,32]
    const float* __restrict__ b_dec,     // [32]
    const float* __restrict__ W_full,    // [32,1]
    const float* __restrict__ b_full,    // [1]
    const float* __restrict__ W_fbeta,   // [64,1]
    const float* __restrict__ b_fbeta,   // [1]
    const float* __restrict__ W_emb,     // [4,4]
    const float* __restrict__ b_emb,     // [4]
    const float* __restrict__ W_ih,      // [5,256]
    const float* __restrict__ b_ih,      // [256]
    const float* __restrict__ W_hh,      // [64,256]
    const float* __restrict__ b_hh,      // [256]
    float* __restrict__ out,             // [nped,64]
    int nped, int npts)
{
    __shared__ unsigned hist[PPB][HROW];
    __shared__ float    h_s[PPB][HD];
    __shared__ float    att2_s[PPB][AD];        // b_dec + b_enc folded in
    __shared__ float    part[PPB][3][6][HD];    // [ped][gate][sixth][lane]

    const int tid  = threadIdx.x;
    const int ped0 = blockIdx.x * PPB;
    const int wave = tid >> 6;    // 0..7
    const int lane = tid & 63;

    // zero histograms (PPB*HROW == 256)
    if (tid < PPB * HROW) ((unsigned*)hist)[tid] = 0u;
    // stage h (PPB*HD == 128)
    if (tid < PPB * HD) {
        int pp = tid >> 6, k = tid & 63;
        int pd = ped0 + pp;
        h_s[pp][k] = (pd < nped) ? h_in[pd * HD + k] : 0.f;
    }

    // ped boxes — block-uniform, forced into SGPRs. Bit-exact vs JAX rounding.
    float px0, py0, px1, py1;
    px0 = rfl(end_pos[ped0 * 2 + 0]); py0 = rfl(end_pos[ped0 * 2 + 1]);
    if (ped0 + 1 < nped) { px1 = rfl(end_pos[ped0 * 2 + 2]); py1 = rfl(end_pos[ped0 * 2 + 3]); }
    else                 { px1 = 1e30f;                      py1 = 1e30f; }
    const float tlx0 = px0 - 1.0f, tly0 = py0 + 1.0f, brx0 = px0 + 1.0f, bry0 = py0 - 1.0f;
    const float tlx1 = px1 - 1.0f, tly1 = py1 + 1.0f, brx1 = px1 + 1.0f, bry1 = py1 - 1.0f;
    __syncthreads();

    // ---- Phase 1: branchless histogram -------------------------------------
    {
        const int dummy = 64 + lane;   // bank-spread discard slot
        auto test = [&](float sx, float sy, int pp,
                        float tlx, float tly, float brx, float bry) {
            // inside == exact complement of reference's outside (strict cmps)
            bool inside = (sx < brx) & (sx > tlx) & (sy < tly) & (sy > bry);
            float cx = floorf((sx - tlx) * 4.0f);
            float cy = floorf((tly - sy) * 4.0f);
            int c = (int)fmaf(cy, 8.0f, cx);       // exact: small ints in fp
            int idx = inside ? c : dummy;
            atomicAdd(&hist[pp][idx], 1u);
        };
        const float4* sc4 = reinterpret_cast<const float4*>(scene);
        const int n4 = npts >> 1;
        #pragma unroll 4
        for (int i = tid; i < n4; i += BLK) {
            float4 s = sc4[i];
            test(s.x, s.y, 0, tlx0, tly0, brx0, bry0);
            test(s.x, s.y, 1, tlx1, tly1, brx1, bry1);
            test(s.z, s.w, 0, tlx0, tly0, brx0, bry0);
            test(s.z, s.w, 1, tlx1, tly1, brx1, bry1);
        }
    }
    __syncthreads();

    float acc_i = 0.f, acc_g = 0.f, acc_o = 0.f;
    const int p = wave;   // ped index for waves 0/1

    if (wave >= 2) {
        // ---- waves 2..7: k-sixth of W_hh, both peds from one load ----------
        const int s  = wave - 2;                 // 0..5
        const int k0 = (s * HD) / 6;
        const int k1 = ((s + 1) * HD) / 6;
        float i0 = 0.f, g0 = 0.f, o0 = 0.f;
        float i1 = 0.f, g1 = 0.f, o1 = 0.f;
        for (int k = k0; k < k1; ++k) {
            float wi = W_hh[k * 256 + lane];
            float wg = W_hh[k * 256 + 128 + lane];
            float wo = W_hh[k * 256 + 192 + lane];
            float h0 = h_s[0][k];
            float h1 = h_s[1][k];
            i0 = fmaf(h0, wi, i0); i1 = fmaf(h1, wi, i1);
            g0 = fmaf(h0, wg, g0); g1 = fmaf(h1, wg, g1);
            o0 = fmaf(h0, wo, o0); o1 = fmaf(h1, wo, o1);
        }
        part[0][0][s][lane] = i0;  part[0][1][s][lane] = g0;  part[0][2][s][lane] = o0;
        part[1][0][s][lane] = i1;  part[1][1][s][lane] = g1;  part[1][2][s][lane] = o1;
    } else if (ped0 + p < nped) {
        // ---- waves 0/1: attention path for ped p ----------------------------
        const int ped = ped0 + p;
        // att2[j] = h . W_dec[:,j], 64 lanes (k split in halves)
        {
            const int col   = lane & 31;
            const int kbase = (lane >> 5) * 32;
            float a = 0.f;
            #pragma unroll 8
            for (int k = 0; k < 32; ++k) {
                int kk = kbase + k;
                a = fmaf(h_s[p][kk], W_dec[kk * AD + col], a);
            }
            a += __shfl_xor(a, 32, 64);
            if (lane < AD) att2_s[p][lane] = a + b_dec[lane] + b_enc[lane];
        }
        // att[c] = sum_j relu(cnt*W_enc[j] + att2[j]) * W_full[j] + b_full
        float cnt = (float)hist[p][lane];
        float att = b_full[0];
        #pragma unroll 8
        for (int j = 0; j < AD; ++j) {
            float sj = fmaf(cnt, W_enc[j], att2_s[p][j]);
            att = fmaf(fmaxf(sj, 0.f), W_full[j], att);
        }
        // softmax over 64 cells: max, then joint (e-sum, cnt*e-sum) reduction
        float m = att;
        #pragma unroll
        for (int off = 32; off; off >>= 1) m = fmaxf(m, __shfl_xor(m, off, 64));
        float e  = __expf(att - m);
        float se = e, sa = cnt * e;
        #pragma unroll
        for (int off = 32; off; off >>= 1) {
            se += __shfl_xor(se, off, 64);
            sa += __shfl_xor(sa, off, 64);
        }
        float awe = sa * __builtin_amdgcn_rcpf(se);

        // gate = sigmoid(h . W_fbeta + b_fbeta)
        float gp = h_s[p][lane] * W_fbeta[lane];
        #pragma unroll
        for (int off = 32; off; off >>= 1) gp += __shfl_xor(gp, off, 64);
        float aweg = fsig(gp + b_fbeta[0]) * awe;

        // x = [emb(4), gated awe] (uniform)
        float dx = disp_pos[ped * 2], dy = disp_pos[ped * 2 + 1];
        float ex = (p == 0) ? px0 : px1;
        float ey = (p == 0) ? py0 : py1;
        float x0 = ex * W_emb[0] + ey * W_emb[4] + dx * W_emb[8]  + dy * W_emb[12] + b_emb[0];
        float x1 = ex * W_emb[1] + ey * W_emb[5] + dx * W_emb[9]  + dy * W_emb[13] + b_emb[1];
        float x2 = ex * W_emb[2] + ey * W_emb[6] + dx * W_emb[10] + dy * W_emb[14] + b_emb[2];
        float x3 = ex * W_emb[3] + ey * W_emb[7] + dx * W_emb[11] + dy * W_emb[15] + b_emb[3];

        acc_i = b_ih[lane]       + b_hh[lane];
        acc_g = b_ih[128 + lane] + b_hh[128 + lane];
        acc_o = b_ih[192 + lane] + b_hh[192 + lane];
        acc_i = fmaf(x0, W_ih[0 * 256 + lane], acc_i);
        acc_g = fmaf(x0, W_ih[0 * 256 + 128 + lane], acc_g);
        acc_o = fmaf(x0, W_ih[0 * 256 + 192 + lane], acc_o);
        acc_i = fmaf(x1, W_ih[1 * 256 + lane], acc_i);
        acc_g = fmaf(x1, W_ih[1 * 256 + 128 + lane], acc_g);
        acc_o = fmaf(x1, W_ih[1 * 256 + 192 + lane], acc_o);
        acc_i = fmaf(x2, W_ih[2 * 256 + lane], acc_i);
        acc_g = fmaf(x2, W_ih[2 * 256 + 128 + lane], acc_g);
        acc_o = fmaf(x2, W_ih[2 * 256 + 192 + lane], acc_o);
        acc_i = fmaf(x3, W_ih[3 * 256 + lane], acc_i);
        acc_g = fmaf(x3, W_ih[3 * 256 + 128 + lane], acc_g);
        acc_o = fmaf(x3, W_ih[3 * 256 + 192 + lane], acc_o);
        acc_i = fmaf(aweg, W_ih[4 * 256 + lane], acc_i);
        acc_g = fmaf(aweg, W_ih[4 * 256 + 128 + lane], acc_g);
        acc_o = fmaf(aweg, W_ih[4 * 256 + 192 + lane], acc_o);
    }
    __syncthreads();

    if (wave < 2 && ped0 + p < nped) {
        #pragma unroll
        for (int s = 0; s < 6; ++s) {
            acc_i += part[p][0][s][lane];
            acc_g += part[p][1][s][lane];
            acc_o += part[p][2][s][lane];
        }
        float cc = fsig(acc_i) * ftanh(acc_g);
        out[(ped0 + p) * HD + lane] = fsig(acc_o) * ftanh(cc);
    }
}

extern "C" void kernel_launch(void* const* d_in, const int* in_sizes, int n_in,
                              void* d_out, int out_size, void* d_ws, size_t ws_size,
                              hipStream_t stream)
{
    const float* scene   = (const float*)d_in[0];
    const float* end_pos = (const float*)d_in[1];
    const float* disp    = (const float*)d_in[2];
    const float* h_in    = (const float*)d_in[3];
    const float* W_enc   = (const float*)d_in[4];
    const float* b_enc   = (const float*)d_in[5];
    const float* W_dec   = (const float*)d_in[6];
    const float* b_dec   = (const float*)d_in[7];
    const float* W_full  = (const float*)d_in[8];
    const float* b_full  = (const float*)d_in[9];
    const float* W_fbeta = (const float*)d_in[10];
    const float* b_fbeta = (const float*)d_in[11];
    const float* W_emb   = (const float*)d_in[12];
    const float* b_emb   = (const float*)d_in[13];
    const float* W_ih    = (const float*)d_in[14];
    const float* b_ih    = (const float*)d_in[15];
    const float* W_hh    = (const float*)d_in[16];
    const float* b_hh    = (const float*)d_in[17];
    float* out = (float*)d_out;

    const int nped = in_sizes[1] / 2;
    const int npts = in_sizes[0] / 2;
    const int blocks = (nped + PPB - 1) / PPB;

    hipLaunchKernelGGL(fused_ssfe_kernel, dim3(blocks), dim3(BLK), 0, stream,
        scene, end_pos, disp, h_in, W_enc, b_enc, W_dec, b_dec, W_full, b_full,
        W_fbeta, b_fbeta, W_emb, b_emb, W_ih, b_ih, W_hh, b_hh, out, nped, npts);
}